// Round 2
// baseline (626.468 us; speedup 1.0000x reference)
//
#include <hip/hip_runtime.h>

typedef unsigned short u16;
typedef __attribute__((ext_vector_type(8))) short bf16x8;
typedef __attribute__((ext_vector_type(4))) float f32x4;

__device__ __forceinline__ float bf2f(u16 b) {
    unsigned int u = ((unsigned int)b) << 16;
    float f;
    __builtin_memcpy(&f, &u, 4);
    return f;
}
__device__ __forceinline__ u16 f2bf(float f) {
    unsigned int u;
    __builtin_memcpy(&u, &f, 4);
    unsigned int r = u + 0x7FFFu + ((u >> 16) & 1u);  // RNE
    return (u16)(r >> 16);
}

__device__ __forceinline__ void async_copy16(const void* g, void* lds) {
    __builtin_amdgcn_global_load_lds(
        (const __attribute__((address_space(1))) unsigned int*)g,
        (__attribute__((address_space(3))) unsigned int*)lds, 16, 0, 0);
}

#define MFMA(a, b, c) __builtin_amdgcn_mfma_f32_16x16x32_bf16((a), (b), (c), 0, 0, 0)

// ---------------------------------------------------------------------------
// Elementwise f32 -> bf16.  n must be a multiple of 2048; grid = n/2048.
// ---------------------------------------------------------------------------
__global__ __launch_bounds__(256) void cvt_f32_bf16(
    const float* __restrict__ src, u16* __restrict__ dst)
{
    int i = (blockIdx.x * 256 + threadIdx.x) * 8;
    float4 a = *(const float4*)(src + i);
    float4 b = *(const float4*)(src + i + 4);
    uint4 o;
    u16* po = (u16*)&o;
    po[0] = f2bf(a.x); po[1] = f2bf(a.y); po[2] = f2bf(a.z); po[3] = f2bf(a.w);
    po[4] = f2bf(b.x); po[5] = f2bf(b.y); po[6] = f2bf(b.z); po[7] = f2bf(b.w);
    *(uint4*)(dst + i) = o;
}

// ---------------------------------------------------------------------------
// Transpose + convert: src f32 [R][C] -> dst bf16 [C][R].  Grid (C/64, R/64).
// ---------------------------------------------------------------------------
__global__ __launch_bounds__(256) void transpose_cvt(
    const float* __restrict__ src, u16* __restrict__ dst, int R, int C)
{
    __shared__ u16 T[64][65];
    int r0 = blockIdx.y * 64, c0 = blockIdx.x * 64;
    int t = threadIdx.x;
#pragma unroll
    for (int i = 0; i < 4; ++i) {
        int c = i * 256 + t;            // 1024 chunks of 4 f32
        int row = c >> 4, col4 = (c & 15) * 4;
        float4 v = *(const float4*)(src + (size_t)(r0 + row) * C + c0 + col4);
        T[row][col4 + 0] = f2bf(v.x);
        T[row][col4 + 1] = f2bf(v.y);
        T[row][col4 + 2] = f2bf(v.z);
        T[row][col4 + 3] = f2bf(v.w);
    }
    __syncthreads();
#pragma unroll
    for (int i = 0; i < 2; ++i) {
        int c = i * 256 + t;            // 512 chunks of 8 bf16
        int row = c >> 3, col8 = (c & 7) * 8;   // row: dst row (=src col)
        uint4 o;
        u16* po = (u16*)&o;
#pragma unroll
        for (int j = 0; j < 8; ++j) po[j] = T[col8 + j][row];
        *(uint4*)(dst + (size_t)(c0 + row) * R + r0 + col8) = o;
    }
}

// ---------------------------------------------------------------------------
// GEMM (B-transposed): C[M][N] = A[M][K] * Bt[N][K]^T, bf16 in, fp32 accum.
// 128x128 tile, BK=64, 256 threads (4 waves, 2x2 of 64x64 per wave).
// XOR-swizzled LDS: slot (row, s) holds global k-chunk s ^ (row&7).
// ---------------------------------------------------------------------------
template <bool F32OUT>
__global__ __launch_bounds__(256) void gemm_bt(
    const u16* __restrict__ A, const u16* __restrict__ Bt, void* __restrict__ Cp,
    int M, int N, int K)
{
    __shared__ u16 As[128][64];
    __shared__ u16 Bs[128][64];
    int tid = threadIdx.x;
    int w = tid >> 6, lane = tid & 63;
    int quad = lane >> 4, l15 = lane & 15;
    int m0 = blockIdx.y * 128, n0 = blockIdx.x * 128;
    int wm = w >> 1, wn = w & 1;

    f32x4 acc[4][4] = {};

    for (int k0 = 0; k0 < K; k0 += 64) {
#pragma unroll
        for (int i = 0; i < 4; ++i) {
            int row = w * 32 + i * 8 + (lane >> 3);
            int s = lane & 7;
            int gc = s ^ (row & 7);
            async_copy16(A + (size_t)(m0 + row) * K + k0 + gc * 8, &As[w * 32 + i * 8][0]);
            async_copy16(Bt + (size_t)(n0 + row) * K + k0 + gc * 8, &Bs[w * 32 + i * 8][0]);
        }
        __syncthreads();
#pragma unroll
        for (int kk = 0; kk < 2; ++kk) {
            bf16x8 a[4], b[4];
            int kq = kk * 4 + quad;
#pragma unroll
            for (int mt = 0; mt < 4; ++mt) {
                int m = wm * 64 + mt * 16 + l15;
                a[mt] = *(const bf16x8*)&As[m][(kq ^ (m & 7)) * 8];
            }
#pragma unroll
            for (int nt = 0; nt < 4; ++nt) {
                int n = wn * 64 + nt * 16 + l15;
                b[nt] = *(const bf16x8*)&Bs[n][(kq ^ (n & 7)) * 8];
            }
#pragma unroll
            for (int mt = 0; mt < 4; ++mt)
#pragma unroll
                for (int nt = 0; nt < 4; ++nt)
                    acc[mt][nt] = MFMA(a[mt], b[nt], acc[mt][nt]);
        }
        __syncthreads();
    }

#pragma unroll
    for (int mt = 0; mt < 4; ++mt)
#pragma unroll
        for (int nt = 0; nt < 4; ++nt)
#pragma unroll
            for (int r = 0; r < 4; ++r) {
                int m = m0 + wm * 64 + mt * 16 + quad * 4 + r;
                int n = n0 + wn * 64 + nt * 16 + l15;
                if (F32OUT)
                    ((float*)Cp)[(size_t)m * N + n] = acc[mt][nt][r];
                else
                    ((u16*)Cp)[(size_t)m * N + n] = f2bf(acc[mt][nt][r]);
            }
}

// ---------------------------------------------------------------------------
// Per-(seq, head) RMSNorm + RoPE for q and k.  One wave per 128-vector.
// QKV bf16 [2048][6144] (q:0..4095, k:4096..5119).
// Qr[32][2048][128], Kr[8][2048][128] (bf16).
// ---------------------------------------------------------------------------
__global__ __launch_bounds__(256) void norm_rope(
    const u16* __restrict__ QKV, const int* __restrict__ pos,
    const float* __restrict__ cosT, const float* __restrict__ sinT,
    const float* __restrict__ qw, const float* __restrict__ kw,
    u16* __restrict__ Qr, u16* __restrict__ Kr)
{
    int gw = blockIdx.x * 4 + (threadIdx.x >> 6);  // 0 .. 2048*40-1
    int lane = threadIdx.x & 63;
    int s = gw / 40;
    int hh = gw - s * 40;
    bool isq = hh < 32;
    int h = isq ? hh : hh - 32;
    int col0 = isq ? h * 128 : 4096 + h * 128;
    const u16* x = QKV + (size_t)s * 6144 + col0;
    float x1 = bf2f(x[lane]);
    float x2 = bf2f(x[lane + 64]);
    float ss = x1 * x1 + x2 * x2;
#pragma unroll
    for (int m = 1; m < 64; m <<= 1) ss += __shfl_xor(ss, m);
    float r = rsqrtf(ss * (1.0f / 128.0f) + 1e-6f);
    const float* wgt = isq ? qw : kw;
    float y1 = x1 * r * wgt[lane];
    float y2 = x2 * r * wgt[lane + 64];
    int p = pos[s];
    float c1 = cosT[p * 128 + lane], c2 = cosT[p * 128 + lane + 64];
    float s1 = sinT[p * 128 + lane], s2 = sinT[p * 128 + lane + 64];
    float o1 = y1 * c1 - y2 * s1;   // rot[d<64] = -y[d+64]
    float o2 = y2 * c2 + y1 * s2;   // rot[d>=64] = y[d-64]
    u16* dst = (isq ? Qr : Kr) + ((size_t)h * 2048 + s) * 128;
    dst[lane] = f2bf(o1);
    dst[lane + 64] = f2bf(o2);
}

// ---------------------------------------------------------------------------
// V transpose: QKV v-part [2048][8*128] -> Vt[8][128][2048].  Grid (32, 8).
// ---------------------------------------------------------------------------
__global__ __launch_bounds__(256) void v_transpose(
    const u16* __restrict__ QKV, u16* __restrict__ Vt)
{
    __shared__ u16 T[64][130];
    int s0 = blockIdx.x * 64;
    int kh = blockIdx.y;
    int t = threadIdx.x;
#pragma unroll
    for (int i = 0; i < 4; ++i) {
        int c = i * 256 + t;                  // 1024 chunks: 64 s-rows x 16 d-chunks
        int srow = c >> 4, d8 = (c & 15) * 8;
        uint4 v = *(const uint4*)(QKV + (size_t)(s0 + srow) * 6144 + 5120 + kh * 128 + d8);
        const u16* pv = (const u16*)&v;
#pragma unroll
        for (int j = 0; j < 8; ++j) T[srow][d8 + j] = pv[j];
    }
    __syncthreads();
#pragma unroll
    for (int i = 0; i < 4; ++i) {
        int c = i * 256 + t;                  // 1024 chunks: 128 d-rows x 8 s-chunks
        int drow = c >> 3, s8 = (c & 7) * 8;
        uint4 o;
        u16* po = (u16*)&o;
#pragma unroll
        for (int j = 0; j < 8; ++j) po[j] = T[s8 + j][drow];
        *(uint4*)(Vt + ((size_t)kh * 128 + drow) * 2048 + s0 + s8) = o;
    }
}

// ---------------------------------------------------------------------------
// Flash attention, causal, GQA (4 q-heads per kv-head).
// Grid (32 q-tiles, 32 heads), 256 threads.  BQ=64 (wave owns 16 rows), BKEY=64.
// Qr[32][2048][128], Kr[8][2048][128], Vt[8][128][2048] -> O[2048][4096] bf16.
// ---------------------------------------------------------------------------
__global__ __launch_bounds__(256) void flash_attn(
    const u16* __restrict__ Qr, const u16* __restrict__ Kr,
    const u16* __restrict__ Vt, u16* __restrict__ O)
{
    __shared__ u16 Ks[64][128];   // [key][d], chunk-swizzled
    __shared__ u16 Vs[128][64];   // [d][key], chunk-swizzled
    __shared__ u16 Ps[4][16][72]; // per-wave P tile [q][key]

    int h = blockIdx.y;
    int qi = blockIdx.x;
    int tid = threadIdx.x;
    int w = tid >> 6, lane = tid & 63;
    int quad = lane >> 4, l15 = lane & 15;
    int kvh = h >> 2;
    int q0 = qi * 64;

    // Q fragments in registers for the whole block
    bf16x8 qf[4];
    const u16* qbase = Qr + ((size_t)h * 2048 + q0 + w * 16 + l15) * 128;
#pragma unroll
    for (int kk = 0; kk < 4; ++kk)
        qf[kk] = *(const bf16x8*)(qbase + kk * 32 + quad * 8);

    float m_i[4], l_i[4];
#pragma unroll
    for (int r = 0; r < 4; ++r) { m_i[r] = -__builtin_inff(); l_i[r] = 0.0f; }
    f32x4 acc_o[8] = {};

    const float scale = 0.08838834764831845f;  // 1/sqrt(128)
    const float L2E = 1.44269504f;

    for (int kt = 0; kt <= qi; ++kt) {
        int k0 = kt * 64;
        // stage K [64][128] and V^T [128][64]
#pragma unroll
        for (int i = 0; i < 4; ++i) {
            int c = (w * 4 + i) * 64 + lane;
            int krow = c >> 4, ks = c & 15;
            int kgc = ks ^ (krow & 7);
            async_copy16(Kr + ((size_t)kvh * 2048 + k0 + krow) * 128 + kgc * 8,
                         &Ks[(w * 4 + i) * 4][0]);
            int vrow = c >> 3, vs = c & 7;
            int vgc = vs ^ (vrow & 7);
            async_copy16(Vt + ((size_t)kvh * 128 + vrow) * 2048 + k0 + vgc * 8,
                         &Vs[(w * 4 + i) * 8][0]);
        }
        __syncthreads();

        // S = Q K^T  (16 q-rows x 64 keys per wave)
        f32x4 sa[4] = {};
#pragma unroll
        for (int nt = 0; nt < 4; ++nt) {
            int krow = nt * 16 + l15;
#pragma unroll
            for (int kk = 0; kk < 4; ++kk) {
                int kq = kk * 4 + quad;
                bf16x8 kf = *(const bf16x8*)&Ks[krow][(kq ^ (krow & 7)) * 8];
                sa[nt] = MFMA(qf[kk], kf, sa[nt]);
            }
        }

        // online softmax
        bool diag = (kt == qi);
        float sv[4][4], pv[4][4], mloc[4];
#pragma unroll
        for (int r = 0; r < 4; ++r) mloc[r] = -__builtin_inff();
#pragma unroll
        for (int nt = 0; nt < 4; ++nt)
#pragma unroll
            for (int r = 0; r < 4; ++r) {
                float v = sa[nt][r] * scale;
                if (diag) {
                    int key = k0 + nt * 16 + l15;
                    int qrow = q0 + w * 16 + quad * 4 + r;
                    if (key > qrow) v = -__builtin_inff();
                }
                sv[nt][r] = v;
                mloc[r] = fmaxf(mloc[r], v);
            }
#pragma unroll
        for (int r = 0; r < 4; ++r) {
#pragma unroll
            for (int m = 1; m < 16; m <<= 1) mloc[r] = fmaxf(mloc[r], __shfl_xor(mloc[r], m));
        }
        float alpha[4];
#pragma unroll
        for (int r = 0; r < 4; ++r) {
            float mnew = fmaxf(m_i[r], mloc[r]);
            alpha[r] = exp2f((m_i[r] - mnew) * L2E);
            m_i[r] = mnew;
            float rs = 0.0f;
#pragma unroll
            for (int nt = 0; nt < 4; ++nt) {
                float p = exp2f((sv[nt][r] - mnew) * L2E);
                pv[nt][r] = p;
                rs += p;
            }
#pragma unroll
            for (int m = 1; m < 16; m <<= 1) rs += __shfl_xor(rs, m);
            l_i[r] = l_i[r] * alpha[r] + rs;
        }
#pragma unroll
        for (int nt = 0; nt < 8; ++nt)
#pragma unroll
            for (int r = 0; r < 4; ++r) acc_o[nt][r] *= alpha[r];

        // P -> LDS (C-layout -> A-layout transform), wave-local
#pragma unroll
        for (int nt = 0; nt < 4; ++nt)
#pragma unroll
            for (int r = 0; r < 4; ++r)
                Ps[w][quad * 4 + r][nt * 16 + l15] = f2bf(pv[nt][r]);
        asm volatile("s_waitcnt lgkmcnt(0)" ::: "memory");

        bf16x8 pf[2];
#pragma unroll
        for (int kk = 0; kk < 2; ++kk)
            pf[kk] = *(const bf16x8*)&Ps[w][l15][kk * 32 + quad * 8];

        // O += P V
#pragma unroll
        for (int nt = 0; nt < 8; ++nt) {
            int vrow = nt * 16 + l15;
#pragma unroll
            for (int kk = 0; kk < 2; ++kk) {
                int kq = kk * 4 + quad;
                bf16x8 vf = *(const bf16x8*)&Vs[vrow][(kq ^ (vrow & 7)) * 8];
                acc_o[nt] = MFMA(pf[kk], vf, acc_o[nt]);
            }
        }
        __syncthreads();
    }

    // epilogue: O[q][h*128+d] = acc / l
#pragma unroll
    for (int nt = 0; nt < 8; ++nt)
#pragma unroll
        for (int r = 0; r < 4; ++r) {
            int qrow = q0 + w * 16 + quad * 4 + r;
            int d = nt * 16 + l15;
            O[(size_t)qrow * 4096 + h * 128 + d] = f2bf(acc_o[nt][r] / l_i[r]);
        }
}

// ---------------------------------------------------------------------------
extern "C" void kernel_launch(void* const* d_in, const int* in_sizes, int n_in,
                              void* d_out, int out_size, void* d_ws, size_t ws_size,
                              hipStream_t stream) {
    const float* x    = (const float*)d_in[0];
    const int*   pos  = (const int*)d_in[1];
    const float* cosT = (const float*)d_in[2];
    const float* sinT = (const float*)d_in[3];
    // d_in[4] attn_mask: causal, applied analytically
    const float* Wq = (const float*)d_in[5];
    const float* Wk = (const float*)d_in[6];
    const float* Wv = (const float*)d_in[7];
    const float* Wo = (const float*)d_in[8];
    const float* qw = (const float*)d_in[9];
    const float* kw = (const float*)d_in[10];
    float* out = (float*)d_out;

    char* ws = (char*)d_ws;
    u16* WT  = (u16*)ws;                                   // [6144][4096] bf16; later Wo^T [4096][4096]
    u16* QKV = (u16*)(ws + 50331648ull);                   // [2048][6144] bf16
    u16* Qr  = (u16*)(ws + 75497472ull);                   // [32][2048][128] bf16
    u16* Kr  = (u16*)(ws + 92274688ull);                   // [8][2048][128] bf16
    u16* Vt  = (u16*)(ws + 96468992ull);                   // [8][128][2048] bf16
    u16* Xb  = (u16*)(ws + 100663296ull);                  // [2048][4096] bf16
    u16* AttnOut = QKV;                                    // reuse (QKV dead after norm/v_transpose)

    dim3 blk(256);
    cvt_f32_bf16<<<dim3(4096), blk, 0, stream>>>(x, Xb);
    transpose_cvt<<<dim3(64, 64), blk, 0, stream>>>(Wq, WT, 4096, 4096);
    transpose_cvt<<<dim3(16, 64), blk, 0, stream>>>(Wk, WT + 4096ull * 4096, 4096, 1024);
    transpose_cvt<<<dim3(16, 64), blk, 0, stream>>>(Wv, WT + 5120ull * 4096, 4096, 1024);
    gemm_bt<false><<<dim3(48, 16), blk, 0, stream>>>(Xb, WT, QKV, 2048, 6144, 4096);
    norm_rope<<<dim3(20480), blk, 0, stream>>>(QKV, pos, cosT, sinT, qw, kw, Qr, Kr);
    v_transpose<<<dim3(32, 8), blk, 0, stream>>>(QKV, Vt);
    transpose_cvt<<<dim3(64, 64), blk, 0, stream>>>(Wo, WT, 4096, 4096);  // Wo^T into WT region
    flash_attn<<<dim3(32, 32), blk, 0, stream>>>(Qr, Kr, Vt, AttnOut);
    gemm_bt<true><<<dim3(32, 16), blk, 0, stream>>>(AttnOut, WT, out, 2048, 4096, 4096);
}

// Round 3
// 552.393 us; speedup vs baseline: 1.1341x; 1.1341x over previous
//
#include <hip/hip_runtime.h>

typedef unsigned short u16;
typedef __attribute__((ext_vector_type(8))) short bf16x8;
typedef __attribute__((ext_vector_type(4))) float f32x4;

__device__ __forceinline__ float bf2f(u16 b) {
    unsigned int u = ((unsigned int)b) << 16;
    float f;
    __builtin_memcpy(&f, &u, 4);
    return f;
}
__device__ __forceinline__ u16 f2bf(float f) {
    unsigned int u;
    __builtin_memcpy(&u, &f, 4);
    unsigned int r = u + 0x7FFFu + ((u >> 16) & 1u);  // RNE
    return (u16)(r >> 16);
}

__device__ __forceinline__ void async_copy16(const void* g, void* lds) {
    __builtin_amdgcn_global_load_lds(
        (const __attribute__((address_space(1))) unsigned int*)g,
        (__attribute__((address_space(3))) unsigned int*)lds, 16, 0, 0);
}

#define MFMA(a, b, c) __builtin_amdgcn_mfma_f32_16x16x32_bf16((a), (b), (c), 0, 0, 0)

// ---------------------------------------------------------------------------
// Elementwise f32 -> bf16.  n must be a multiple of 2048; grid = n/2048.
// ---------------------------------------------------------------------------
__global__ __launch_bounds__(256) void cvt_f32_bf16(
    const float* __restrict__ src, u16* __restrict__ dst)
{
    int i = (blockIdx.x * 256 + threadIdx.x) * 8;
    float4 a = *(const float4*)(src + i);
    float4 b = *(const float4*)(src + i + 4);
    uint4 o;
    u16* po = (u16*)&o;
    po[0] = f2bf(a.x); po[1] = f2bf(a.y); po[2] = f2bf(a.z); po[3] = f2bf(a.w);
    po[4] = f2bf(b.x); po[5] = f2bf(b.y); po[6] = f2bf(b.z); po[7] = f2bf(b.w);
    *(uint4*)(dst + i) = o;
}

// ---------------------------------------------------------------------------
// Transpose + convert: src f32 [R][C] -> dst bf16 [C][R].  Grid (C/64, R/64).
// ---------------------------------------------------------------------------
__global__ __launch_bounds__(256) void transpose_cvt(
    const float* __restrict__ src, u16* __restrict__ dst, int R, int C)
{
    __shared__ u16 T[64][65];
    int r0 = blockIdx.y * 64, c0 = blockIdx.x * 64;
    int t = threadIdx.x;
#pragma unroll
    for (int i = 0; i < 4; ++i) {
        int c = i * 256 + t;            // 1024 chunks of 4 f32
        int row = c >> 4, col4 = (c & 15) * 4;
        float4 v = *(const float4*)(src + (size_t)(r0 + row) * C + c0 + col4);
        T[row][col4 + 0] = f2bf(v.x);
        T[row][col4 + 1] = f2bf(v.y);
        T[row][col4 + 2] = f2bf(v.z);
        T[row][col4 + 3] = f2bf(v.w);
    }
    __syncthreads();
#pragma unroll
    for (int i = 0; i < 2; ++i) {
        int c = i * 256 + t;            // 512 chunks of 8 bf16
        int row = c >> 3, col8 = (c & 7) * 8;   // row: dst row (=src col)
        uint4 o;
        u16* po = (u16*)&o;
#pragma unroll
        for (int j = 0; j < 8; ++j) po[j] = T[col8 + j][row];
        *(uint4*)(dst + (size_t)(c0 + row) * R + r0 + col8) = o;
    }
}

// ---------------------------------------------------------------------------
// GEMM (B-transposed): C[M][N] = A[M][K] * Bt[N][K]^T, bf16 in, fp32 accum.
// 128x128 tile, BK=64, 256 threads (4 waves, 2x2 of 64x64 per wave).
// XOR-swizzled LDS: slot (row, s) holds global k-chunk s ^ (row&7).
// ---------------------------------------------------------------------------
template <bool F32OUT>
__global__ __launch_bounds__(256) void gemm_bt(
    const u16* __restrict__ A, const u16* __restrict__ Bt, void* __restrict__ Cp,
    int M, int N, int K)
{
    __shared__ u16 As[128][64];
    __shared__ u16 Bs[128][64];
    int tid = threadIdx.x;
    int w = tid >> 6, lane = tid & 63;
    int quad = lane >> 4, l15 = lane & 15;
    int m0 = blockIdx.y * 128, n0 = blockIdx.x * 128;
    int wm = w >> 1, wn = w & 1;

    f32x4 acc[4][4] = {};

    for (int k0 = 0; k0 < K; k0 += 64) {
#pragma unroll
        for (int i = 0; i < 4; ++i) {
            int row = w * 32 + i * 8 + (lane >> 3);
            int s = lane & 7;
            int gc = s ^ (row & 7);
            async_copy16(A + (size_t)(m0 + row) * K + k0 + gc * 8, &As[w * 32 + i * 8][0]);
            async_copy16(Bt + (size_t)(n0 + row) * K + k0 + gc * 8, &Bs[w * 32 + i * 8][0]);
        }
        __syncthreads();
#pragma unroll
        for (int kk = 0; kk < 2; ++kk) {
            bf16x8 a[4], b[4];
            int kq = kk * 4 + quad;
#pragma unroll
            for (int mt = 0; mt < 4; ++mt) {
                int m = wm * 64 + mt * 16 + l15;
                a[mt] = *(const bf16x8*)&As[m][(kq ^ (m & 7)) * 8];
            }
#pragma unroll
            for (int nt = 0; nt < 4; ++nt) {
                int n = wn * 64 + nt * 16 + l15;
                b[nt] = *(const bf16x8*)&Bs[n][(kq ^ (n & 7)) * 8];
            }
#pragma unroll
            for (int mt = 0; mt < 4; ++mt)
#pragma unroll
                for (int nt = 0; nt < 4; ++nt)
                    acc[mt][nt] = MFMA(a[mt], b[nt], acc[mt][nt]);
        }
        __syncthreads();
    }

#pragma unroll
    for (int mt = 0; mt < 4; ++mt)
#pragma unroll
        for (int nt = 0; nt < 4; ++nt)
#pragma unroll
            for (int r = 0; r < 4; ++r) {
                int m = m0 + wm * 64 + mt * 16 + quad * 4 + r;
                int n = n0 + wn * 64 + nt * 16 + l15;
                if (F32OUT)
                    ((float*)Cp)[(size_t)m * N + n] = acc[mt][nt][r];
                else
                    ((u16*)Cp)[(size_t)m * N + n] = f2bf(acc[mt][nt][r]);
            }
}

// ---------------------------------------------------------------------------
// Per-(seq, head) RMSNorm + RoPE for q and k.  One wave per 128-vector.
// ---------------------------------------------------------------------------
__global__ __launch_bounds__(256) void norm_rope(
    const u16* __restrict__ QKV, const int* __restrict__ pos,
    const float* __restrict__ cosT, const float* __restrict__ sinT,
    const float* __restrict__ qw, const float* __restrict__ kw,
    u16* __restrict__ Qr, u16* __restrict__ Kr)
{
    int gw = blockIdx.x * 4 + (threadIdx.x >> 6);  // 0 .. 2048*40-1
    int lane = threadIdx.x & 63;
    int s = gw / 40;
    int hh = gw - s * 40;
    bool isq = hh < 32;
    int h = isq ? hh : hh - 32;
    int col0 = isq ? h * 128 : 4096 + h * 128;
    const u16* x = QKV + (size_t)s * 6144 + col0;
    float x1 = bf2f(x[lane]);
    float x2 = bf2f(x[lane + 64]);
    float ss = x1 * x1 + x2 * x2;
#pragma unroll
    for (int m = 1; m < 64; m <<= 1) ss += __shfl_xor(ss, m);
    float r = rsqrtf(ss * (1.0f / 128.0f) + 1e-6f);
    const float* wgt = isq ? qw : kw;
    float y1 = x1 * r * wgt[lane];
    float y2 = x2 * r * wgt[lane + 64];
    int p = pos[s];
    float c1 = cosT[p * 128 + lane], c2 = cosT[p * 128 + lane + 64];
    float s1 = sinT[p * 128 + lane], s2 = sinT[p * 128 + lane + 64];
    float o1 = y1 * c1 - y2 * s1;
    float o2 = y2 * c2 + y1 * s2;
    u16* dst = (isq ? Qr : Kr) + ((size_t)h * 2048 + s) * 128;
    dst[lane] = f2bf(o1);
    dst[lane + 64] = f2bf(o2);
}

// ---------------------------------------------------------------------------
// V transpose: QKV v-part [2048][8*128] -> Vt[8][128][2048].  Grid (32, 8).
// ---------------------------------------------------------------------------
__global__ __launch_bounds__(256) void v_transpose(
    const u16* __restrict__ QKV, u16* __restrict__ Vt)
{
    __shared__ u16 T[64][130];
    int s0 = blockIdx.x * 64;
    int kh = blockIdx.y;
    int t = threadIdx.x;
#pragma unroll
    for (int i = 0; i < 4; ++i) {
        int c = i * 256 + t;
        int srow = c >> 4, d8 = (c & 15) * 8;
        uint4 v = *(const uint4*)(QKV + (size_t)(s0 + srow) * 6144 + 5120 + kh * 128 + d8);
        const u16* pv = (const u16*)&v;
#pragma unroll
        for (int j = 0; j < 8; ++j) T[srow][d8 + j] = pv[j];
    }
    __syncthreads();
#pragma unroll
    for (int i = 0; i < 4; ++i) {
        int c = i * 256 + t;
        int drow = c >> 3, s8 = (c & 7) * 8;
        uint4 o;
        u16* po = (u16*)&o;
#pragma unroll
        for (int j = 0; j < 8; ++j) po[j] = T[s8 + j][drow];
        *(uint4*)(Vt + ((size_t)kh * 128 + drow) * 2048 + s0 + s8) = o;
    }
}

// ---------------------------------------------------------------------------
// Flash attention v2, causal, GQA.
// Block = (kvh, 32-q-row tile); the block's 4 waves are the 4 q-heads of the
// group, sharing K/V staging.  BKEY=64, double-buffered K/V (prefetch issued
// after the barrier), one barrier per K-tile.  LDS = 80 KB -> 2 blocks/CU.
// Grid (64, 8); flat ids f and f+256 map to complementary q-tiles (qt, 63-qt)
// so the two blocks co-resident on a CU sum to ~constant work.
// Qr[32][2048][128], Kr[8][2048][128], Vt[8][128][2048] -> O[2048][4096] bf16.
// ---------------------------------------------------------------------------
__global__ __launch_bounds__(256, 2) void flash_attn2(
    const u16* __restrict__ Qr, const u16* __restrict__ Kr,
    const u16* __restrict__ Vt, u16* __restrict__ O)
{
    __shared__ u16 Ks[2][64][128];   // [buf][key][d], chunk-swizzled
    __shared__ u16 Vs[2][128][64];   // [buf][d][key], chunk-swizzled
    __shared__ u16 Ps[4][32][64];    // per-wave P tile [q][key], chunk-swizzled

    int f = blockIdx.x + 64 * blockIdx.y;    // 0..511
    int lo = f & 255, hi = f >> 8;
    int qt  = hi ? 63 - (lo & 63) : (lo & 63);
    int kvh = (lo >> 6) + hi * 4;

    int tid = threadIdx.x;
    int w = tid >> 6, lane = tid & 63;
    int quad = lane >> 4, l15 = lane & 15;
    int h = kvh * 4 + w;                     // this wave's q-head
    int q0 = qt * 32;
    int nkt = qt / 2 + 1;                    // # of 64-key tiles (causal)

    // Q fragments (32 rows x 128 d per wave) in registers for the whole block
    bf16x8 qf[2][4];
#pragma unroll
    for (int mt = 0; mt < 2; ++mt) {
        const u16* qb = Qr + ((size_t)h * 2048 + q0 + mt * 16 + l15) * 128;
#pragma unroll
        for (int kk = 0; kk < 4; ++kk)
            qf[mt][kk] = *(const bf16x8*)(qb + kk * 32 + quad * 8);
    }

    float m_i[8], l_i[8];
#pragma unroll
    for (int r = 0; r < 8; ++r) { m_i[r] = -__builtin_inff(); l_i[r] = 0.0f; }
    f32x4 acc[2][8] = {};

    const float scale = 0.08838834764831845f;  // 1/sqrt(128)
    const float L2E = 1.44269504f;

    // stage key-tile kt into buffer b (wave-cooperative, 4 rounds each)
    auto stage = [&](int kt, int b) {
        int k0 = kt * 64;
#pragma unroll
        for (int i = 0; i < 4; ++i) {
            int idx = (w * 4 + i) * 64 + lane;
            int krow = idx >> 4, kp = idx & 15;
            int kg = (kp & 8) | ((kp ^ krow) & 7);
            async_copy16(Kr + ((size_t)kvh * 2048 + k0 + krow) * 128 + kg * 8,
                         &Ks[b][(w * 4 + i) * 4][0]);
            int vrow = idx >> 3, vp = idx & 7;
            int vg = vp ^ (vrow & 7);
            async_copy16(Vt + ((size_t)kvh * 128 + vrow) * 2048 + k0 + vg * 8,
                         &Vs[b][(w * 4 + i) * 8][0]);
        }
    };

    stage(0, 0);

    for (int kt = 0; kt < nkt; ++kt) {
        int b = kt & 1;
        int k0 = kt * 64;
        __syncthreads();                    // buf b ready (vmcnt drained)
        if (kt + 1 < nkt) stage(kt + 1, b ^ 1);   // prefetch overlaps compute

        // S = Q K^T : 32 q-rows x 64 keys per wave
        f32x4 sa[2][4] = {};
#pragma unroll
        for (int nt = 0; nt < 4; ++nt) {
            int krow = nt * 16 + l15;
#pragma unroll
            for (int kk = 0; kk < 4; ++kk) {
                int kq = kk * 4 + quad;
                int kph = (kq & 8) | ((kq ^ krow) & 7);
                bf16x8 kf = *(const bf16x8*)&Ks[b][krow][kph * 8];
                sa[0][nt] = MFMA(qf[0][kk], kf, sa[0][nt]);
                sa[1][nt] = MFMA(qf[1][kk], kf, sa[1][nt]);
            }
        }

        // online softmax (8 q-rows per lane: (mt, r))
        bool last = (kt == nkt - 1);
        float pv[2][4][4], mloc[8];
#pragma unroll
        for (int r = 0; r < 8; ++r) mloc[r] = -__builtin_inff();
#pragma unroll
        for (int mt = 0; mt < 2; ++mt)
#pragma unroll
            for (int nt = 0; nt < 4; ++nt)
#pragma unroll
                for (int r = 0; r < 4; ++r) {
                    float v = sa[mt][nt][r] * scale;
                    if (last) {
                        int key = k0 + nt * 16 + l15;
                        int qrow = q0 + mt * 16 + quad * 4 + r;
                        if (key > qrow) v = -__builtin_inff();
                    }
                    pv[mt][nt][r] = v;
                    mloc[mt * 4 + r] = fmaxf(mloc[mt * 4 + r], v);
                }
#pragma unroll
        for (int r = 0; r < 8; ++r)
#pragma unroll
            for (int m = 1; m < 16; m <<= 1)
                mloc[r] = fmaxf(mloc[r], __shfl_xor(mloc[r], m));

        float alpha[8];
#pragma unroll
        for (int mt = 0; mt < 2; ++mt)
#pragma unroll
            for (int r = 0; r < 4; ++r) {
                int rr = mt * 4 + r;
                float mnew = fmaxf(m_i[rr], mloc[rr]);
                alpha[rr] = exp2f((m_i[rr] - mnew) * L2E);
                m_i[rr] = mnew;
                float rs = 0.0f;
#pragma unroll
                for (int nt = 0; nt < 4; ++nt) {
                    float p = exp2f((pv[mt][nt][r] - mnew) * L2E);
                    pv[mt][nt][r] = p;
                    rs += p;
                }
#pragma unroll
                for (int m = 1; m < 16; m <<= 1) rs += __shfl_xor(rs, m);
                l_i[rr] = l_i[rr] * alpha[rr] + rs;
            }
#pragma unroll
        for (int mt = 0; mt < 2; ++mt)
#pragma unroll
            for (int nt = 0; nt < 8; ++nt)
#pragma unroll
                for (int r = 0; r < 4; ++r) acc[mt][nt][r] *= alpha[mt * 4 + r];

        // P -> LDS (C-layout -> A-layout), wave-local, chunk-swizzled
#pragma unroll
        for (int mt = 0; mt < 2; ++mt)
#pragma unroll
            for (int nt = 0; nt < 4; ++nt)
#pragma unroll
                for (int r = 0; r < 4; ++r) {
                    int row = mt * 16 + quad * 4 + r;
                    int col = nt * 16 + l15;
                    int ph = ((col >> 3) ^ (row & 7)) * 8 + (col & 7);
                    Ps[w][row][ph] = f2bf(pv[mt][nt][r]);
                }
        asm volatile("s_waitcnt lgkmcnt(0)" ::: "memory");

        bf16x8 pf[2][2];
#pragma unroll
        for (int mt = 0; mt < 2; ++mt) {
            int row = mt * 16 + l15;
#pragma unroll
            for (int kk = 0; kk < 2; ++kk)
                pf[mt][kk] = *(const bf16x8*)&Ps[w][row][((kk * 4 + quad) ^ (row & 7)) * 8];
        }

        // O += P V
#pragma unroll
        for (int nt = 0; nt < 8; ++nt) {
            int vrow = nt * 16 + l15;
#pragma unroll
            for (int kk = 0; kk < 2; ++kk) {
                int vph = (kk * 4 + quad) ^ (vrow & 7);
                bf16x8 vf = *(const bf16x8*)&Vs[b][vrow][vph * 8];
                acc[0][nt] = MFMA(pf[0][kk], vf, acc[0][nt]);
                acc[1][nt] = MFMA(pf[1][kk], vf, acc[1][nt]);
            }
        }
    }

    // epilogue
#pragma unroll
    for (int mt = 0; mt < 2; ++mt)
#pragma unroll
        for (int nt = 0; nt < 8; ++nt)
#pragma unroll
            for (int r = 0; r < 4; ++r) {
                int qrow = q0 + mt * 16 + quad * 4 + r;
                int d = nt * 16 + l15;
                O[(size_t)qrow * 4096 + h * 128 + d] =
                    f2bf(acc[mt][nt][r] / l_i[mt * 4 + r]);
            }
}

// ---------------------------------------------------------------------------
extern "C" void kernel_launch(void* const* d_in, const int* in_sizes, int n_in,
                              void* d_out, int out_size, void* d_ws, size_t ws_size,
                              hipStream_t stream) {
    const float* x    = (const float*)d_in[0];
    const int*   pos  = (const int*)d_in[1];
    const float* cosT = (const float*)d_in[2];
    const float* sinT = (const float*)d_in[3];
    // d_in[4] attn_mask: causal, applied analytically
    const float* Wq = (const float*)d_in[5];
    const float* Wk = (const float*)d_in[6];
    const float* Wv = (const float*)d_in[7];
    const float* Wo = (const float*)d_in[8];
    const float* qw = (const float*)d_in[9];
    const float* kw = (const float*)d_in[10];
    float* out = (float*)d_out;

    char* ws = (char*)d_ws;
    u16* WT  = (u16*)ws;                                   // [6144][4096] bf16; later Wo^T
    u16* QKV = (u16*)(ws + 50331648ull);                   // [2048][6144] bf16
    u16* Qr  = (u16*)(ws + 75497472ull);                   // [32][2048][128] bf16
    u16* Kr  = (u16*)(ws + 92274688ull);                   // [8][2048][128] bf16
    u16* Vt  = (u16*)(ws + 96468992ull);                   // [8][128][2048] bf16
    u16* Xb  = (u16*)(ws + 100663296ull);                  // [2048][4096] bf16
    u16* AttnOut = QKV;                                    // reuse

    dim3 blk(256);
    cvt_f32_bf16<<<dim3(4096), blk, 0, stream>>>(x, Xb);
    transpose_cvt<<<dim3(64, 64), blk, 0, stream>>>(Wq, WT, 4096, 4096);
    transpose_cvt<<<dim3(16, 64), blk, 0, stream>>>(Wk, WT + 4096ull * 4096, 4096, 1024);
    transpose_cvt<<<dim3(16, 64), blk, 0, stream>>>(Wv, WT + 5120ull * 4096, 4096, 1024);
    gemm_bt<false><<<dim3(48, 16), blk, 0, stream>>>(Xb, WT, QKV, 2048, 6144, 4096);
    norm_rope<<<dim3(20480), blk, 0, stream>>>(QKV, pos, cosT, sinT, qw, kw, Qr, Kr);
    v_transpose<<<dim3(32, 8), blk, 0, stream>>>(QKV, Vt);
    transpose_cvt<<<dim3(64, 64), blk, 0, stream>>>(Wo, WT, 4096, 4096);  // Wo^T
    flash_attn2<<<dim3(64, 8), blk, 0, stream>>>(Qr, Kr, Vt, AttnOut);
    gemm_bt<true><<<dim3(32, 16), blk, 0, stream>>>(AttnOut, WT, out, 2048, 4096, 4096);
}